// Round 5
// baseline (520.560 us; speedup 1.0000x reference)
//
#include <hip/hip_runtime.h>
#include <hip/hip_fp16.h>

#define NB 4
#define NN 20000
#define NE 320000
#define ND 64
#define NR 64
#define NT 1000
#define NL 6
#define LN_EPS 1e-5f
#define CAP 64   // bucket capacity: deg ~ Poisson(16), P(deg>64) ~ 5e-19

typedef _Float16 half8 __attribute__((ext_vector_type(8)));
typedef _Float16 half4v __attribute__((ext_vector_type(4)));
typedef float floatx4 __attribute__((ext_vector_type(4)));

// State: fp16 [N,B,D] node-major; a (n,b) row = exactly one 128B line.
// r18 = r16 (R4's LDS rel staging reverted: FETCH_SIZE unchanged proved
// rel was already L2-resident; the fill+occupancy drop cost 20%) +
// BATCH-PHASED edge loop: for b in 0..3, gather only the (src,b) 128B
// line. Per-b x slice = 2.56MB < 4MB per-XCD L2, and all blocks phase
// through b together -> x-gathers become L2 hits instead of the 60MB/layer
// of L2 misses (the latency wall R1/R3/R4 couldn't move). x-gather bytes
// also drop 164->41MB/layer. Edge fields: two uniform v_readlane + per-
// half cndmask (2 edges/iter, no DS broadcast).

// ---------------------------------------------------------------- prep 1
// blocks [0,79): zero cnt ; [79,271): conv_w transpose ; 271: query ;
// [272,656): rel_mlp all layers (wave-local, wave = batch)
__global__ void __launch_bounds__(256)
prep1(int* __restrict__ cnt,
      const float* __restrict__ cw, _Float16* __restrict__ cwt,
      const float* __restrict__ relrep, const int* __restrict__ r_index,
      float* __restrict__ query,
      const float* __restrict__ rp_w1, const float* __restrict__ rp_b1,
      const float* __restrict__ rp_w2, const float* __restrict__ rp_b2,
      __half* __restrict__ rel16) {
    int blk = blockIdx.x, tid = threadIdx.x;
    if (blk < 79) {
        int i = blk * 256 + tid;
        if (i < NN) cnt[i] = 0;
    } else if (blk < 271) {
        int i = (blk - 79) * 256 + tid;             // NL*128*64 = 192*256
        int l = i >> 13, rem = i & 8191, k = rem >> 6, n = rem & 63;
        cwt[l * 8192 + n * 128 + k] = (_Float16)cw[i];
    } else if (blk == 271) {
        int b = tid >> 6, d = tid & 63;
        query[tid] = relrep[(b * NR + r_index[b]) * ND + d];
    } else {
        int u = blk - 272;                          // 0..383 = l*NR + r
        int l = u >> 6, r = u & 63;
        int b = tid >> 6, j = tid & 63;
        const float* w1 = rp_w1 + l * ND * ND;
        const float* w2 = rp_w2 + l * ND * ND;
        float xin = relrep[(b * NR + r) * ND + j];
        float acc = rp_b1[l * ND + j];
        #pragma unroll 8
        for (int k = 0; k < ND; ++k) acc += __shfl(xin, k) * w1[k * ND + j];
        float hmid = fmaxf(acc, 0.f);
        float outv = rp_b2[l * ND + j];
        #pragma unroll 8
        for (int k = 0; k < ND; ++k) outv += __shfl(hmid, k) * w2[k * ND + j];
        rel16[l * (NR * NB * ND) + (r * NB + b) * ND + j] = __float2half(outv);
    }
}

// ---------------------------------------------------------------- prep 2
// one pass: bucket-scatter edges by dst
__global__ void __launch_bounds__(256)
prep2(const int* __restrict__ ei, const int* __restrict__ et,
      const float* __restrict__ ew, int* __restrict__ cnt,
      int4* __restrict__ epack) {
    int e = blockIdx.x * 256 + threadIdx.x;         // NE = 1250*256 exactly
    int d = ei[NE + e];
    int p = atomicAdd(&cnt[d], 1);
    if (p < CAP)
        epack[d * CAP + p] = make_int4(ei[e], et[e], __float_as_int(ew[e]), 0);
}

__device__ __forceinline__ float2 h2f(unsigned u) {
    __half2 h = *(__half2*)&u;
    return __half22float2(h);
}
__device__ __forceinline__ __half2 u2h2(unsigned u) { return *(__half2*)&u; }

// --------------------------------------------- shared epilogue (MFMA+LN)
// A16g/sDg are this 4-wave subgroup's tiles; wvl in [0,4).
__device__ __forceinline__ void conv_ln_epilogue(
        _Float16* A16g, float* sDg, int wvl, int lane, int n,
        const _Float16* __restrict__ cwt, const float* __restrict__ cb,
        const float* __restrict__ g, const float* __restrict__ bb,
        __half* __restrict__ xo16) {
    __syncthreads();
    {
        int m = lane & 15, quad = lane >> 4;
        int ncol = wvl * 16 + m;
        floatx4 acc = {0.f, 0.f, 0.f, 0.f};
        #pragma unroll
        for (int k0 = 0; k0 < 128; k0 += 32) {
            half8 a = *(const half8*)&A16g[m * 136 + k0 + quad * 8];
            half8 bfr = *(const half8*)&cwt[ncol * 128 + k0 + quad * 8];
            acc = __builtin_amdgcn_mfma_f32_16x16x32_f16(a, bfr, acc, 0, 0, 0);
        }
        #pragma unroll
        for (int rg = 0; rg < 4; ++rg)
            sDg[(quad * 4 + rg) * 65 + ncol] = acc[rg];
    }
    __syncthreads();
    float gl = g[lane], bl = bb[lane], cbl = cb[lane];
    #pragma unroll
    for (int b = 0; b < NB; ++b) {
        float acc = sDg[(wvl * 4 + b) * 65 + lane] + cbl;
        float s = acc, s2 = acc * acc;
        #pragma unroll
        for (int o = 32; o > 0; o >>= 1) { s += __shfl_xor(s, o); s2 += __shfl_xor(s2, o); }
        float mu  = s * (1.f / ND);
        float var = s2 * (1.f / ND) - mu * mu;
        float hn  = (acc - mu) * rsqrtf(var + LN_EPS) * gl + bl;
        float xvf = (float)A16g[(wvl * 4 + b) * 136 + lane];
        float v   = fmaxf(hn, 0.f) + xvf;
        xo16[(n * NB + b) * ND + lane] = __float2half(v);
    }
}

// ------------------------------------------------ layer 1 (x0 query-sparse)
// R3 form: 256 threads / 4 nodes; rel gathers are L2-resident (32KB).
__global__ void __launch_bounds__(256)
fused_layer_first(const __half* __restrict__ rel16,
                  const int* __restrict__ cnt, const int4* __restrict__ epack,
                  const float* __restrict__ query, const int* __restrict__ h_index,
                  const _Float16* __restrict__ cwt, const float* __restrict__ cb,
                  const float* __restrict__ g, const float* __restrict__ bb,
                  __half* __restrict__ xo16) {
    __shared__ _Float16 A16[16 * 136];
    __shared__ float sD[16 * 65];
    int wv = threadIdx.x >> 6;
    int lane = threadIdx.x & 63;
    int n = blockIdx.x * 4 + wv;
    int cn = __builtin_amdgcn_readfirstlane(min(cnt[n], CAP));
    int bidx = lane >> 4, c4 = (lane & 15) << 2;
    int hb = h_index[bidx];

    const uint2* __restrict__ r2 = (const uint2*)rel16;
    float4 q4 = ((const float4*)query)[lane];
    half4v qh;
    qh.x = (_Float16)q4.x; qh.y = (_Float16)q4.y;
    qh.z = (_Float16)q4.z; qh.w = (_Float16)q4.w;
    float qx = (float)qh.x, qy = (float)qh.y, qz = (float)qh.z, qw = (float)qh.w;

    float4 agg4 = make_float4(0.f, 0.f, 0.f, 0.f);
    {
        int4 ed = make_int4(0, 0, 0, 0);
        if (lane < cn) ed = epack[n * CAP + lane];
        for (int j = 0; j < cn; ++j) {
            int s   = __builtin_amdgcn_readlane(ed.x, j);
            int t   = __builtin_amdgcn_readlane(ed.y, j);
            float w = __int_as_float(__builtin_amdgcn_readlane(ed.z, j));
            if (s == hb) {
                uint2 ra = r2[t * 64 + lane];
                float2 q0 = h2f(ra.x), q1 = h2f(ra.y);
                agg4.x = fmaf(qx * q0.x, w, agg4.x);
                agg4.y = fmaf(qy * q0.y, w, agg4.y);
                agg4.z = fmaf(qz * q1.x, w, agg4.z);
                agg4.w = fmaf(qw * q1.y, w, agg4.w);
            }
        }
    }
    if (n == hb) {
        agg4.x += q4.x; agg4.y += q4.y; agg4.z += q4.z; agg4.w += q4.w;
    }
    {
        int r = wv * 4 + bidx;
        half4v xh = {0, 0, 0, 0};
        if (n == hb) xh = qh;
        *(half4v*)&A16[r * 136 + c4] = xh;
        half4v ah;
        ah.x = (_Float16)agg4.x; ah.y = (_Float16)agg4.y;
        ah.z = (_Float16)agg4.z; ah.w = (_Float16)agg4.w;
        *(half4v*)&A16[r * 136 + 64 + c4] = ah;
    }
    conv_ln_epilogue(A16, sD, wv, lane, n, cwt, cb, g, bb, xo16);
}

// ------------------------------------------------ generic fused layer
// 512 threads = 8 waves = 8 nodes. Batch-phased: for b in 0..3, lanes
// 0-31 handle even edges, 32-63 odd edges; each half-wave gathers ONE
// 128B (src,b) line (uint/lane). Per-b working set 2.56MB -> per-XCD
// L2-resident. Edge fields: 2 uniform readlanes + cndmask select.
__global__ void __launch_bounds__(512)
fused_layer(const __half* __restrict__ x16, const __half* __restrict__ rel16,
            const int* __restrict__ cnt, const int4* __restrict__ epack,
            const float* __restrict__ query, const int* __restrict__ h_index,
            const _Float16* __restrict__ cwt, const float* __restrict__ cb,
            const float* __restrict__ g, const float* __restrict__ bb,
            __half* __restrict__ xo16) {
    __shared__ _Float16 A16[2][16 * 136];
    __shared__ float sD[2][16 * 65];
    int tid = threadIdx.x;
    int wv = tid >> 6, lane = tid & 63;
    int grp = wv >> 2, wvl = wv & 3;
    int n = blockIdx.x * 8 + wv;
    int cn = __builtin_amdgcn_readfirstlane(min(cnt[n], CAP));
    int hf = lane >> 5, sub = lane & 31;

    const uint* __restrict__ xu = (const uint*)x16;     // 4B = 2 halves
    const uint* __restrict__ ru = (const uint*)rel16;

    int4 ed = make_int4(0, 0, 0, 0);
    if (lane < cn) ed = epack[n * CAP + lane];

    for (int b = 0; b < NB; ++b) {
        float ax = 0.f, ay = 0.f;
        for (int j = 0; j < cn; j += 2) {
            // edge j -> lanes 0-31, edge j+1 -> lanes 32-63.
            // j+1 >= cn reads a zeroed lane: w=0 -> exact +0.
            int s0 = __builtin_amdgcn_readlane(ed.x, j);
            int s1 = __builtin_amdgcn_readlane(ed.x, j + 1);
            int t0 = __builtin_amdgcn_readlane(ed.y, j);
            int t1 = __builtin_amdgcn_readlane(ed.y, j + 1);
            int w0 = __builtin_amdgcn_readlane(ed.z, j);
            int w1 = __builtin_amdgcn_readlane(ed.z, j + 1);
            int s = hf ? s1 : s0;
            int t = hf ? t1 : t0;
            float w = __int_as_float(hf ? w1 : w0);
            uint xa = xu[(s * NB + b) * 32 + sub];
            uint ra = ru[(t * NB + b) * 32 + sub];
            __half2 p = __hmul2(u2h2(xa), u2h2(ra));
            ax = fmaf(__low2float(p),  w, ax);
            ay = fmaf(__high2float(p), w, ay);
        }
        ax += __shfl_xor(ax, 32);
        ay += __shfl_xor(ay, 32);
        if (n == h_index[b]) {
            float2 q = ((const float2*)query)[b * 32 + sub];
            ax += q.x; ay += q.y;
        }
        int r = wvl * 4 + b;
        if (hf == 0) {
            __half2 ah;
            ah.x = __float2half(ax); ah.y = __float2half(ay);
            *(__half2*)&A16[grp][r * 136 + 64 + 2 * sub] = ah;
            uint xr = xu[(n * NB + b) * 32 + sub];      // concat x half
            *(uint*)&A16[grp][r * 136 + 2 * sub] = xr;
        }
    }
    conv_ln_epilogue(A16[grp], sD[grp], wvl, lane, n, cwt, cb, g, bb, xo16);
}

// score[b,t] = relu(concat(x[ti,b,:],query[b,:]) @ W1 + b1) @ W2 + b2
__global__ void final_score(const __half* __restrict__ x16, const float* __restrict__ query,
                            const int* __restrict__ t_index,
                            const float* __restrict__ w1, const float* __restrict__ b1,
                            const float* __restrict__ w2, const float* __restrict__ b2,
                            float* __restrict__ out) {
    int gid = blockIdx.x * 4 + (threadIdx.x >> 6);
    int lane = threadIdx.x & 63;
    int b = gid / NT;
    int ti = t_index[gid];
    float xv = __half2float(x16[(ti * NB + b) * ND + lane]);
    float qv = query[b * ND + lane];
    float a0 = b1[lane], a1 = b1[lane + 64];
    #pragma unroll 8
    for (int k = 0; k < ND; ++k) {
        float f = __shfl(xv, k);
        a0 += f * w1[k * 128 + lane];
        a1 += f * w1[k * 128 + lane + 64];
    }
    #pragma unroll 8
    for (int k = 0; k < ND; ++k) {
        float f = __shfl(qv, k);
        a0 += f * w1[(ND + k) * 128 + lane];
        a1 += f * w1[(ND + k) * 128 + lane + 64];
    }
    a0 = fmaxf(a0, 0.f);
    a1 = fmaxf(a1, 0.f);
    float p = a0 * w2[lane] + a1 * w2[lane + 64];
    #pragma unroll
    for (int o = 32; o > 0; o >>= 1) p += __shfl_xor(p, o);
    if (lane == 0) out[gid] = p + b2[0];
}

extern "C" void kernel_launch(void* const* d_in, const int* in_sizes, int n_in,
                              void* d_out, int out_size, void* d_ws, size_t ws_size,
                              hipStream_t stream) {
    const int*   edge_index  = (const int*)d_in[0];
    const int*   edge_type   = (const int*)d_in[1];
    const float* relrep      = (const float*)d_in[2];
    const int*   h_index     = (const int*)d_in[3];
    const int*   r_index     = (const int*)d_in[4];
    const int*   t_index     = (const int*)d_in[5];
    const float* edge_weight = (const float*)d_in[6];
    const float* rp_w1  = (const float*)d_in[7];
    const float* rp_b1  = (const float*)d_in[8];
    const float* rp_w2  = (const float*)d_in[9];
    const float* rp_b2  = (const float*)d_in[10];
    const float* conv_w = (const float*)d_in[11];
    const float* conv_b = (const float*)d_in[12];
    const float* ln_g   = (const float*)d_in[13];
    const float* ln_b   = (const float*)d_in[14];
    const float* mlp_w1 = (const float*)d_in[15];
    const float* mlp_b1 = (const float*)d_in[16];
    const float* mlp_w2 = (const float*)d_in[17];
    const float* mlp_b2 = (const float*)d_in[18];
    float* out = (float*)d_out;

    const int BND = NB * NN * ND;              // 5,120,000
    const int RELSZ = NR * NB * ND;            // 16384
    float*    ws     = (float*)d_ws;
    float*    query  = ws;                         // 256 f
    __half*   rel16  = (__half*)(query + 256);     // NL*RELSZ halves
    __half*   x16a   = rel16 + NL * RELSZ;         // BND halves
    __half*   x16b   = x16a + BND;                 // BND halves
    _Float16* cwt16  = (_Float16*)(x16b + BND);    // NL*8192 halves
    int4*     epack  = (int4*)(cwt16 + NL * 8192); // NN*CAP int4 (20.5 MB)
    int*      cnt    = (int*)(epack + NN * CAP);   // NN
    // total ≈ 42 MB

    // 9-dispatch graph
    prep1<<<656, 256, 0, stream>>>(cnt, conv_w, cwt16, relrep, r_index, query,
                                   rp_w1, rp_b1, rp_w2, rp_b2, rel16);
    prep2<<<NE / 256, 256, 0, stream>>>(edge_index, edge_type, edge_weight,
                                        cnt, epack);

    __half* mc = x16a; __half* mn = x16b;
    fused_layer_first<<<NN / 4, 256, 0, stream>>>(rel16, cnt, epack,
                                                  query, h_index,
                                                  cwt16, conv_b, ln_g, ln_b, mc);
    for (int l = 1; l < NL; ++l) {
        fused_layer<<<NN / 8, 512, 0, stream>>>(mc, rel16 + l * RELSZ, cnt, epack,
                                                query, h_index,
                                                cwt16 + l * 8192, conv_b + l * ND,
                                                ln_g + l * ND, ln_b + l * ND, mn);
        __half* th = mc; mc = mn; mn = th;
    }
    final_score<<<NB * NT / 4, 256, 0, stream>>>(mc, query, t_index,
                                                 mlp_w1, mlp_b1, mlp_w2, mlp_b2, out);
}

// Round 6
// 441.475 us; speedup vs baseline: 1.1791x; 1.1791x over previous
//
#include <hip/hip_runtime.h>
#include <hip/hip_fp16.h>

#define NB 4
#define NN 20000
#define NE 320000
#define ND 64
#define NR 64
#define NT 1000
#define NL 6
#define LN_EPS 1e-5f
#define CAP 64   // bucket capacity: deg ~ Poisson(16), P(deg>64) ~ 5e-19

typedef _Float16 half8 __attribute__((ext_vector_type(8)));
typedef _Float16 half4v __attribute__((ext_vector_type(4)));
typedef float floatx4 __attribute__((ext_vector_type(4)));

// State: fp16 [B][N][D] BATCH-major; an (b,n) row = one 128B line.
// r19: spatial batch->XCD partition. fused_layer block = ONE batch b
// (b = (blk&7)>>1 -> XCD pair {2b,2b+1} under round-robin dispatch) x
// 16 nodes. Per-XCD x working set = 2.56MB slice < 4MB L2, cutting the
// ~53MB/layer cross-XCD duplication (FETCH invariant that bound R0-R5)
// to ~20MB. LN/conv are per-(n,b) independent -> per-b epilogue in-block,
// no agg round-trip. epack int4->int2 (src|type<<16, weight): halves
// edge-table fetch. 512thr/8 waves; half-wave = node; 1 line/edge.

// ---------------------------------------------------------------- prep 1
// blocks [0,79): zero cnt ; [79,271): conv_w transpose ; 271: query ;
// [272,656): rel_mlp all layers (wave-local, wave = batch)
__global__ void __launch_bounds__(256)
prep1(int* __restrict__ cnt,
      const float* __restrict__ cw, _Float16* __restrict__ cwt,
      const float* __restrict__ relrep, const int* __restrict__ r_index,
      float* __restrict__ query,
      const float* __restrict__ rp_w1, const float* __restrict__ rp_b1,
      const float* __restrict__ rp_w2, const float* __restrict__ rp_b2,
      __half* __restrict__ rel16) {
    int blk = blockIdx.x, tid = threadIdx.x;
    if (blk < 79) {
        int i = blk * 256 + tid;
        if (i < NN) cnt[i] = 0;
    } else if (blk < 271) {
        int i = (blk - 79) * 256 + tid;             // NL*128*64 = 192*256
        int l = i >> 13, rem = i & 8191, k = rem >> 6, n = rem & 63;
        cwt[l * 8192 + n * 128 + k] = (_Float16)cw[i];
    } else if (blk == 271) {
        int b = tid >> 6, d = tid & 63;
        query[tid] = relrep[(b * NR + r_index[b]) * ND + d];
    } else {
        int u = blk - 272;                          // 0..383 = l*NR + r
        int l = u >> 6, r = u & 63;
        int b = tid >> 6, j = tid & 63;
        const float* w1 = rp_w1 + l * ND * ND;
        const float* w2 = rp_w2 + l * ND * ND;
        float xin = relrep[(b * NR + r) * ND + j];
        float acc = rp_b1[l * ND + j];
        #pragma unroll 8
        for (int k = 0; k < ND; ++k) acc += __shfl(xin, k) * w1[k * ND + j];
        float hmid = fmaxf(acc, 0.f);
        float outv = rp_b2[l * ND + j];
        #pragma unroll 8
        for (int k = 0; k < ND; ++k) outv += __shfl(hmid, k) * w2[k * ND + j];
        // batch-major rel: [l][(b*NR + r)][j]
        rel16[l * (NR * NB * ND) + (b * NR + r) * ND + j] = __float2half(outv);
    }
}

// ---------------------------------------------------------------- prep 2
// one pass: bucket-scatter edges by dst; 8B records {src|type<<16, w}
__global__ void __launch_bounds__(256)
prep2(const int* __restrict__ ei, const int* __restrict__ et,
      const float* __restrict__ ew, int* __restrict__ cnt,
      int2* __restrict__ ep2) {
    int e = blockIdx.x * 256 + threadIdx.x;         // NE = 1250*256 exactly
    int d = ei[NE + e];
    int p = atomicAdd(&cnt[d], 1);
    if (p < CAP)
        ep2[d * CAP + p] = make_int2(ei[e] | (et[e] << 16),
                                     __float_as_int(ew[e]));
}

__device__ __forceinline__ float2 h2f(unsigned u) {
    __half2 h = *(__half2*)&u;
    return __half22float2(h);
}
__device__ __forceinline__ __half2 u2h2(unsigned u) { return *(__half2*)&u; }

// --------------------------------------------- first-layer epilogue (4 waves)
__device__ __forceinline__ void conv_ln_epilogue4(
        _Float16* A16, float* sD, int wv, int lane, int n,
        const _Float16* __restrict__ cwt, const float* __restrict__ cb,
        const float* __restrict__ g, const float* __restrict__ bb,
        __half* __restrict__ xo16) {
    __syncthreads();
    {
        int m = lane & 15, quad = lane >> 4;
        int ncol = wv * 16 + m;
        floatx4 acc = {0.f, 0.f, 0.f, 0.f};
        #pragma unroll
        for (int k0 = 0; k0 < 128; k0 += 32) {
            half8 a = *(const half8*)&A16[m * 136 + k0 + quad * 8];
            half8 bfr = *(const half8*)&cwt[ncol * 128 + k0 + quad * 8];
            acc = __builtin_amdgcn_mfma_f32_16x16x32_f16(a, bfr, acc, 0, 0, 0);
        }
        #pragma unroll
        for (int rg = 0; rg < 4; ++rg)
            sD[(quad * 4 + rg) * 65 + ncol] = acc[rg];
    }
    __syncthreads();
    float gl = g[lane], bl = bb[lane], cbl = cb[lane];
    #pragma unroll
    for (int b = 0; b < NB; ++b) {
        float acc = sD[(wv * 4 + b) * 65 + lane] + cbl;
        float s = acc, s2 = acc * acc;
        #pragma unroll
        for (int o = 32; o > 0; o >>= 1) { s += __shfl_xor(s, o); s2 += __shfl_xor(s2, o); }
        float mu  = s * (1.f / ND);
        float var = s2 * (1.f / ND) - mu * mu;
        float hn  = (acc - mu) * rsqrtf(var + LN_EPS) * gl + bl;
        float xvf = (float)A16[(wv * 4 + b) * 136 + lane];
        float v   = fmaxf(hn, 0.f) + xvf;
        xo16[(b * NN + n) * ND + lane] = __float2half(v);   // batch-major
    }
}

// ------------------------------------------------ layer 1 (x0 query-sparse)
// 256 threads / 4 nodes; rel gathers L2-resident (32KB).
__global__ void __launch_bounds__(256)
fused_layer_first(const __half* __restrict__ rel16,
                  const int* __restrict__ cnt, const int2* __restrict__ ep2,
                  const float* __restrict__ query, const int* __restrict__ h_index,
                  const _Float16* __restrict__ cwt, const float* __restrict__ cb,
                  const float* __restrict__ g, const float* __restrict__ bb,
                  __half* __restrict__ xo16) {
    __shared__ _Float16 A16[16 * 136];
    __shared__ float sD[16 * 65];
    int wv = threadIdx.x >> 6;
    int lane = threadIdx.x & 63;
    int n = blockIdx.x * 4 + wv;
    int cn = __builtin_amdgcn_readfirstlane(min(cnt[n], CAP));
    int bidx = lane >> 4, c4 = (lane & 15) << 2;
    int hb = h_index[bidx];

    const uint2* __restrict__ r2 = (const uint2*)rel16;
    float4 q4 = ((const float4*)query)[lane];
    half4v qh;
    qh.x = (_Float16)q4.x; qh.y = (_Float16)q4.y;
    qh.z = (_Float16)q4.z; qh.w = (_Float16)q4.w;
    float qx = (float)qh.x, qy = (float)qh.y, qz = (float)qh.z, qw = (float)qh.w;

    float4 agg4 = make_float4(0.f, 0.f, 0.f, 0.f);
    {
        int2 ed = make_int2(0, 0);
        if (lane < cn) ed = ep2[n * CAP + lane];
        for (int j = 0; j < cn; ++j) {
            int p   = __builtin_amdgcn_readlane(ed.x, j);
            float w = __int_as_float(__builtin_amdgcn_readlane(ed.y, j));
            int s = p & 0xffff, t = p >> 16;
            if (s == hb) {
                // batch-major rel row (bidx, t): 16 uint2 per row
                uint2 ra = r2[(bidx * NR + t) * 16 + (lane & 15)];
                float2 q0 = h2f(ra.x), q1 = h2f(ra.y);
                agg4.x = fmaf(qx * q0.x, w, agg4.x);
                agg4.y = fmaf(qy * q0.y, w, agg4.y);
                agg4.z = fmaf(qz * q1.x, w, agg4.z);
                agg4.w = fmaf(qw * q1.y, w, agg4.w);
            }
        }
    }
    if (n == hb) {
        agg4.x += q4.x; agg4.y += q4.y; agg4.z += q4.z; agg4.w += q4.w;
    }
    {
        int r = wv * 4 + bidx;
        half4v xh = {0, 0, 0, 0};
        if (n == hb) xh = qh;
        *(half4v*)&A16[r * 136 + c4] = xh;
        half4v ah;
        ah.x = (_Float16)agg4.x; ah.y = (_Float16)agg4.y;
        ah.z = (_Float16)agg4.z; ah.w = (_Float16)agg4.w;
        *(half4v*)&A16[r * 136 + 64 + c4] = ah;
    }
    conv_ln_epilogue4(A16, sD, wv, lane, n, cwt, cb, g, bb, xo16);
}

// ------------------------------------------------ generic fused layer
// 512 threads = 8 waves = 16 (node) units, ONE batch b per block.
// b = (blk&7)>>1 -> under round-robin dispatch, batch b occupies XCD
// pair {2b,2b+1}; per-XCD x slice (2.56MB) is L2-resident. Half-wave
// owns one node: per edge ONE 128B line gather (32 lanes x uint).
__global__ void __launch_bounds__(512)
fused_layer(const __half* __restrict__ x16, const __half* __restrict__ rel16,
            const int* __restrict__ cnt, const int2* __restrict__ ep2,
            const float* __restrict__ query, const int* __restrict__ h_index,
            const _Float16* __restrict__ cwt, const float* __restrict__ cb,
            const float* __restrict__ g, const float* __restrict__ bb,
            __half* __restrict__ xo16) {
    __shared__ _Float16 A16[16 * 136];
    __shared__ float sD[16 * 65];
    int tid = threadIdx.x;
    int wv = tid >> 6, lane = tid & 63;
    int hf = lane >> 5, sub = lane & 31;
    int blk = blockIdx.x;
    int b = (blk & 7) >> 1;                 // batch = XCD pair
    int i = ((blk >> 3) << 1) + (blk & 1);  // 0..1249 within batch
    int node_base = i * 16;
    int r = wv * 2 + hf;                    // A16 row 0..15
    int n = node_base + r;                  // this half-wave's node
    int cnH = min(cnt[n], CAP);             // uniform per half-wave
    int cmax = max(cnH, __shfl_xor(cnH, 32));
    int hb = h_index[b];

    const uint* __restrict__ xu = (const uint*)x16;     // 4B = 2 halves
    const uint* __restrict__ ru = (const uint*)rel16;

    float ax = 0.f, ay = 0.f;
    for (int c0 = 0; c0 < cmax; c0 += 32) {
        int2 ed = make_int2(0, 0);
        int idx = c0 + sub;
        if (idx < cnH) ed = ep2[n * CAP + idx];
        int jend = min(cmax - c0, 32);
        for (int j = 0; j < jend; ++j) {
            // unit A's edge j in lane j, unit B's in lane 32+j
            int pA = __builtin_amdgcn_readlane(ed.x, j);
            int pB = __builtin_amdgcn_readlane(ed.x, j + 32);
            int wA = __builtin_amdgcn_readlane(ed.y, j);
            int wB = __builtin_amdgcn_readlane(ed.y, j + 32);
            int p   = hf ? pB : pA;
            float w = __int_as_float(hf ? wB : wA);
            int s = p & 0xffff, t = p >> 16;     // zero-pad -> s=t=0, w=0
            uint xa = xu[(b * NN + s) * 32 + sub];
            uint ra = ru[(b * NR + t) * 32 + sub];
            __half2 pr = __hmul2(u2h2(xa), u2h2(ra));
            ax = fmaf(__low2float(pr),  w, ax);
            ay = fmaf(__high2float(pr), w, ay);
        }
    }
    if (n == hb) {
        float2 q = ((const float2*)query)[b * 32 + sub];
        ax += q.x; ay += q.y;
    }
    {
        __half2 ah;
        ah.x = __float2half(ax); ah.y = __float2half(ay);
        *(__half2*)&A16[r * 136 + 64 + 2 * sub] = ah;
        uint xr = xu[(b * NN + n) * 32 + sub];          // concat x half
        *(uint*)&A16[r * 136 + 2 * sub] = xr;
    }
    __syncthreads();
    if (wv < 4) {                       // MFMA: 4 waves cover 64 cols
        int m = lane & 15, quad = lane >> 4;
        int ncol = wv * 16 + m;
        floatx4 acc4 = {0.f, 0.f, 0.f, 0.f};
        #pragma unroll
        for (int k0 = 0; k0 < 128; k0 += 32) {
            half8 a = *(const half8*)&A16[m * 136 + k0 + quad * 8];
            half8 bfr = *(const half8*)&cwt[ncol * 128 + k0 + quad * 8];
            acc4 = __builtin_amdgcn_mfma_f32_16x16x32_f16(a, bfr, acc4, 0, 0, 0);
        }
        #pragma unroll
        for (int rg = 0; rg < 4; ++rg)
            sD[(quad * 4 + rg) * 65 + ncol] = acc4[rg];
    }
    __syncthreads();
    // LN: 8 waves x 2 rows
    float gl = g[lane], bl = bb[lane], cbl = cb[lane];
    #pragma unroll
    for (int r2i = 0; r2i < 2; ++r2i) {
        int row = wv * 2 + r2i;
        int nn = node_base + row;
        float acc = sD[row * 65 + lane] + cbl;
        float s = acc, s2 = acc * acc;
        #pragma unroll
        for (int o = 32; o > 0; o >>= 1) { s += __shfl_xor(s, o); s2 += __shfl_xor(s2, o); }
        float mu  = s * (1.f / ND);
        float var = s2 * (1.f / ND) - mu * mu;
        float hn  = (acc - mu) * rsqrtf(var + LN_EPS) * gl + bl;
        float xvf = (float)A16[row * 136 + lane];
        float v   = fmaxf(hn, 0.f) + xvf;
        xo16[(b * NN + nn) * ND + lane] = __float2half(v);
    }
}

// score[b,t] = relu(concat(x[b,ti,:],query[b,:]) @ W1 + b1) @ W2 + b2
__global__ void final_score(const __half* __restrict__ x16, const float* __restrict__ query,
                            const int* __restrict__ t_index,
                            const float* __restrict__ w1, const float* __restrict__ b1,
                            const float* __restrict__ w2, const float* __restrict__ b2,
                            float* __restrict__ out) {
    int gid = blockIdx.x * 4 + (threadIdx.x >> 6);
    int lane = threadIdx.x & 63;
    int b = gid / NT;
    int ti = t_index[gid];
    float xv = __half2float(x16[(b * NN + ti) * ND + lane]);
    float qv = query[b * ND + lane];
    float a0 = b1[lane], a1 = b1[lane + 64];
    #pragma unroll 8
    for (int k = 0; k < ND; ++k) {
        float f = __shfl(xv, k);
        a0 += f * w1[k * 128 + lane];
        a1 += f * w1[k * 128 + lane + 64];
    }
    #pragma unroll 8
    for (int k = 0; k < ND; ++k) {
        float f = __shfl(qv, k);
        a0 += f * w1[(ND + k) * 128 + lane];
        a1 += f * w1[(ND + k) * 128 + lane + 64];
    }
    a0 = fmaxf(a0, 0.f);
    a1 = fmaxf(a1, 0.f);
    float p = a0 * w2[lane] + a1 * w2[lane + 64];
    #pragma unroll
    for (int o = 32; o > 0; o >>= 1) p += __shfl_xor(p, o);
    if (lane == 0) out[gid] = p + b2[0];
}

extern "C" void kernel_launch(void* const* d_in, const int* in_sizes, int n_in,
                              void* d_out, int out_size, void* d_ws, size_t ws_size,
                              hipStream_t stream) {
    const int*   edge_index  = (const int*)d_in[0];
    const int*   edge_type   = (const int*)d_in[1];
    const float* relrep      = (const float*)d_in[2];
    const int*   h_index     = (const int*)d_in[3];
    const int*   r_index     = (const int*)d_in[4];
    const int*   t_index     = (const int*)d_in[5];
    const float* edge_weight = (const float*)d_in[6];
    const float* rp_w1  = (const float*)d_in[7];
    const float* rp_b1  = (const float*)d_in[8];
    const float* rp_w2  = (const float*)d_in[9];
    const float* rp_b2  = (const float*)d_in[10];
    const float* conv_w = (const float*)d_in[11];
    const float* conv_b = (const float*)d_in[12];
    const float* ln_g   = (const float*)d_in[13];
    const float* ln_b   = (const float*)d_in[14];
    const float* mlp_w1 = (const float*)d_in[15];
    const float* mlp_b1 = (const float*)d_in[16];
    const float* mlp_w2 = (const float*)d_in[17];
    const float* mlp_b2 = (const float*)d_in[18];
    float* out = (float*)d_out;

    const int BND = NB * NN * ND;              // 5,120,000
    const int RELSZ = NR * NB * ND;            // 16384
    float*    ws     = (float*)d_ws;
    float*    query  = ws;                         // 256 f
    __half*   rel16  = (__half*)(query + 256);     // NL*RELSZ halves
    __half*   x16a   = rel16 + NL * RELSZ;         // BND halves
    __half*   x16b   = x16a + BND;                 // BND halves
    _Float16* cwt16  = (_Float16*)(x16b + BND);    // NL*8192 halves
    int2*     epack  = (int2*)(cwt16 + NL * 8192); // NN*CAP int2 (10.2 MB)
    int*      cnt    = (int*)(epack + NN * CAP);   // NN
    // total ≈ 32 MB

    // 9-dispatch graph
    prep1<<<656, 256, 0, stream>>>(cnt, conv_w, cwt16, relrep, r_index, query,
                                   rp_w1, rp_b1, rp_w2, rp_b2, rel16);
    prep2<<<NE / 256, 256, 0, stream>>>(edge_index, edge_type, edge_weight,
                                        cnt, epack);

    __half* mc = x16a; __half* mn = x16b;
    fused_layer_first<<<NN / 4, 256, 0, stream>>>(rel16, cnt, epack,
                                                  query, h_index,
                                                  cwt16, conv_b, ln_g, ln_b, mc);
    for (int l = 1; l < NL; ++l) {
        fused_layer<<<NN / 16 * NB, 512, 0, stream>>>(mc, rel16 + l * RELSZ, cnt, epack,
                                                      query, h_index,
                                                      cwt16 + l * 8192, conv_b + l * ND,
                                                      ln_g + l * ND, ln_b + l * ND, mn);
        __half* th = mc; mc = mn; mn = th;
    }
    final_score<<<NB * NT / 4, 256, 0, stream>>>(mc, query, t_index,
                                                 mlp_w1, mlp_b1, mlp_w2, mlp_b2, out);
}

// Round 8
// 420.057 us; speedup vs baseline: 1.2393x; 1.0510x over previous
//
#include <hip/hip_runtime.h>
#include <hip/hip_fp16.h>

#define NB 4
#define NN 20000
#define NE 320000
#define ND 64
#define NR 64
#define NT 1000
#define NL 6
#define LN_EPS 1e-5f
#define CAP 64   // bucket capacity: deg ~ Poisson(16), P(deg>64) ~ 5e-19

typedef _Float16 half8 __attribute__((ext_vector_type(8)));
typedef _Float16 half4v __attribute__((ext_vector_type(4)));
typedef float floatx4 __attribute__((ext_vector_type(4)));
typedef int sv16 __attribute__((ext_vector_type(16)));

// State: fp16 [B][N][D] batch-major; (b,n) row = one 128B line.
// r21 = r20 with the s_load fix: the edge-table address is laundered
// through readfirstlane so the whole chain is compiler-uniform and the
// s_load_dwordx16 gets an SGPR-pair address (r20 died on v[4:5] there).
// waitcnt folded into the same asm so consumers of ch order correctly.
// Edge metadata -> SGPRs, SALU extract; per (edge,batch) instance the
// lane does 2 ushort gathers + v_mul_f16 + v_fma_mix (~2 VALU vs R6 9.5).

// ---------------------------------------------------------------- prep 1
// blocks [0,79): zero cnt ; [79,271): conv_w transpose ; 271: query ;
// [272,656): rel_mlp ; [656,3156): zero epack (int4 x 640000)
__global__ void __launch_bounds__(256)
prep1(int* __restrict__ cnt, int4* __restrict__ ep4,
      const float* __restrict__ cw, _Float16* __restrict__ cwt,
      const float* __restrict__ relrep, const int* __restrict__ r_index,
      float* __restrict__ query,
      const float* __restrict__ rp_w1, const float* __restrict__ rp_b1,
      const float* __restrict__ rp_w2, const float* __restrict__ rp_b2,
      __half* __restrict__ rel16) {
    int blk = blockIdx.x, tid = threadIdx.x;
    if (blk < 79) {
        int i = blk * 256 + tid;
        if (i < NN) cnt[i] = 0;
    } else if (blk < 271) {
        int i = (blk - 79) * 256 + tid;             // NL*128*64 = 192*256
        int l = i >> 13, rem = i & 8191, k = rem >> 6, n = rem & 63;
        cwt[l * 8192 + n * 128 + k] = (_Float16)cw[i];
    } else if (blk == 271) {
        int b = tid >> 6, d = tid & 63;
        query[tid] = relrep[(b * NR + r_index[b]) * ND + d];
    } else if (blk < 656) {
        int u = blk - 272;                          // 0..383 = l*NR + r
        int l = u >> 6, r = u & 63;
        int b = tid >> 6, j = tid & 63;
        const float* w1 = rp_w1 + l * ND * ND;
        const float* w2 = rp_w2 + l * ND * ND;
        float xin = relrep[(b * NR + r) * ND + j];
        float acc = rp_b1[l * ND + j];
        #pragma unroll 8
        for (int k = 0; k < ND; ++k) acc += __shfl(xin, k) * w1[k * ND + j];
        float hmid = fmaxf(acc, 0.f);
        float outv = rp_b2[l * ND + j];
        #pragma unroll 8
        for (int k = 0; k < ND; ++k) outv += __shfl(hmid, k) * w2[k * ND + j];
        // batch-major rel: [l][(b*NR + r)][j]
        rel16[l * (NR * NB * ND) + (b * NR + r) * ND + j] = __float2half(outv);
    } else {
        int idx = (blk - 656) * 256 + tid;          // 640000 int4 = 10.2MB
        ep4[idx] = make_int4(0, 0, 0, 0);
    }
}

// ---------------------------------------------------------------- prep 2
// bucket-scatter edges by dst; 8B records {src|type<<16, half(w)}
__global__ void __launch_bounds__(256)
prep2(const int* __restrict__ ei, const int* __restrict__ et,
      const float* __restrict__ ew, int* __restrict__ cnt,
      int2* __restrict__ ep2) {
    int e = blockIdx.x * 256 + threadIdx.x;         // NE = 1250*256 exactly
    int d = ei[NE + e];
    int p = atomicAdd(&cnt[d], 1);
    if (p < CAP)
        ep2[d * CAP + p] = make_int2(ei[e] | (et[e] << 16),
                                     (int)__half_as_ushort(__float2half(ew[e])));
}

__device__ __forceinline__ float2 h2f(unsigned u) {
    __half2 h = *(__half2*)&u;
    return __half22float2(h);
}

// --------------------------------------------- first-layer epilogue (4 waves)
__device__ __forceinline__ void conv_ln_epilogue4(
        _Float16* A16, float* sD, int wv, int lane, int n,
        const _Float16* __restrict__ cwt, const float* __restrict__ cb,
        const float* __restrict__ g, const float* __restrict__ bb,
        __half* __restrict__ xo16) {
    __syncthreads();
    {
        int m = lane & 15, quad = lane >> 4;
        int ncol = wv * 16 + m;
        floatx4 acc = {0.f, 0.f, 0.f, 0.f};
        #pragma unroll
        for (int k0 = 0; k0 < 128; k0 += 32) {
            half8 a = *(const half8*)&A16[m * 136 + k0 + quad * 8];
            half8 bfr = *(const half8*)&cwt[ncol * 128 + k0 + quad * 8];
            acc = __builtin_amdgcn_mfma_f32_16x16x32_f16(a, bfr, acc, 0, 0, 0);
        }
        #pragma unroll
        for (int rg = 0; rg < 4; ++rg)
            sD[(quad * 4 + rg) * 65 + ncol] = acc[rg];
    }
    __syncthreads();
    float gl = g[lane], bl = bb[lane], cbl = cb[lane];
    #pragma unroll
    for (int b = 0; b < NB; ++b) {
        float acc = sD[(wv * 4 + b) * 65 + lane] + cbl;
        float s = acc, s2 = acc * acc;
        #pragma unroll
        for (int o = 32; o > 0; o >>= 1) { s += __shfl_xor(s, o); s2 += __shfl_xor(s2, o); }
        float mu  = s * (1.f / ND);
        float var = s2 * (1.f / ND) - mu * mu;
        float hn  = (acc - mu) * rsqrtf(var + LN_EPS) * gl + bl;
        float xvf = (float)A16[(wv * 4 + b) * 136 + lane];
        float v   = fmaxf(hn, 0.f) + xvf;
        xo16[(b * NN + n) * ND + lane] = __float2half(v);   // batch-major
    }
}

// ------------------------------------------------ layer 1 (x0 query-sparse)
__global__ void __launch_bounds__(256)
fused_layer_first(const __half* __restrict__ rel16,
                  const int* __restrict__ cnt, const int2* __restrict__ ep2,
                  const float* __restrict__ query, const int* __restrict__ h_index,
                  const _Float16* __restrict__ cwt, const float* __restrict__ cb,
                  const float* __restrict__ g, const float* __restrict__ bb,
                  __half* __restrict__ xo16) {
    __shared__ _Float16 A16[16 * 136];
    __shared__ float sD[16 * 65];
    int wv = threadIdx.x >> 6;
    int lane = threadIdx.x & 63;
    int n = blockIdx.x * 4 + wv;
    int cn = __builtin_amdgcn_readfirstlane(min(cnt[n], CAP));
    int bidx = lane >> 4, c4 = (lane & 15) << 2;
    int hb = h_index[bidx];

    const uint2* __restrict__ r2 = (const uint2*)rel16;
    float4 q4 = ((const float4*)query)[lane];
    half4v qh;
    qh.x = (_Float16)q4.x; qh.y = (_Float16)q4.y;
    qh.z = (_Float16)q4.z; qh.w = (_Float16)q4.w;
    float qx = (float)qh.x, qy = (float)qh.y, qz = (float)qh.z, qw = (float)qh.w;

    float4 agg4 = make_float4(0.f, 0.f, 0.f, 0.f);
    {
        int2 ed = make_int2(0, 0);
        if (lane < cn) ed = ep2[n * CAP + lane];
        for (int j = 0; j < cn; ++j) {
            int p    = __builtin_amdgcn_readlane(ed.x, j);
            int wraw = __builtin_amdgcn_readlane(ed.y, j);
            float w = __half2float(__ushort_as_half((unsigned short)(wraw & 0xffff)));
            int s = p & 0xffff, t = ((unsigned)p) >> 16;
            if (s == hb) {
                uint2 ra = r2[(bidx * NR + t) * 16 + (lane & 15)];
                float2 q0 = h2f(ra.x), q1 = h2f(ra.y);
                agg4.x = fmaf(qx * q0.x, w, agg4.x);
                agg4.y = fmaf(qy * q0.y, w, agg4.y);
                agg4.z = fmaf(qz * q1.x, w, agg4.z);
                agg4.w = fmaf(qw * q1.y, w, agg4.w);
            }
        }
    }
    if (n == hb) {
        agg4.x += q4.x; agg4.y += q4.y; agg4.z += q4.z; agg4.w += q4.w;
    }
    {
        int r = wv * 4 + bidx;
        half4v xh = {0, 0, 0, 0};
        if (n == hb) xh = qh;
        *(half4v*)&A16[r * 136 + c4] = xh;
        half4v ah;
        ah.x = (_Float16)agg4.x; ah.y = (_Float16)agg4.y;
        ah.z = (_Float16)agg4.z; ah.w = (_Float16)agg4.w;
        *(half4v*)&A16[r * 136 + 64 + c4] = ah;
    }
    conv_ln_epilogue4(A16, sD, wv, lane, n, cwt, cb, g, bb, xo16);
}

// ------------------------------------------------ generic fused layer
// 512 thr = 8 waves = 8 nodes, ONE batch/block (b = (blk&7)>>1 -> XCD
// pair). Wave = node: 64 lanes = the 128B row. Edge metadata via
// s_load_dwordx16 (8 edges) into SGPRs off a readfirstlane-laundered
// (scalar) address; SALU extract; per edge 2 ushort gathers + mul_f16
// + fma_mix. Pad edges are zero records -> exact +0.
__global__ void __launch_bounds__(512)
fused_layer(const __half* __restrict__ x16, const __half* __restrict__ rel16,
            const int* __restrict__ cnt, const int2* __restrict__ ep2,
            const float* __restrict__ query, const int* __restrict__ h_index,
            const _Float16* __restrict__ cwt, const float* __restrict__ cb,
            const float* __restrict__ g, const float* __restrict__ bb,
            __half* __restrict__ xo16) {
    __shared__ _Float16 A16[16 * 136];   // rows 8..15 unused (MFMA don't-care)
    __shared__ float sD[16 * 65];
    int tid = threadIdx.x;
    int wv = tid >> 6, lane = tid & 63;
    int blk = blockIdx.x;
    int b = (blk & 7) >> 1;                 // batch = XCD pair
    int i = ((blk >> 3) << 1) + (blk & 1);  // 0..2499 within batch
    int n = i * 8 + wv;                     // this wave's node
    int cn = __builtin_amdgcn_readfirstlane(min(cnt[n], CAP));
    int hb = h_index[b];

    const ushort* __restrict__ xu = (const ushort*)x16;
    const ushort* __restrict__ ru = (const ushort*)rel16;
    int base_x = b * (NN * ND) + lane;
    int base_r = b * (NR * ND) + lane;

    // own-row concat half — independent load, issue early
    ushort xown = xu[n * ND + base_x];

    float acc = 0.f;
    {
        // scalar (SGPR) edge-table pointer: launder wave-uniform offset
        const int2* pn = ep2 + __builtin_amdgcn_readfirstlane(n * CAP);
        int nch = (cn + 7) >> 3;
        for (int c = 0; c < nch; ++c) {
            const int2* pc = pn + c * 8;
            sv16 ch;
            asm volatile("s_load_dwordx16 %0, %1, 0x0\n\t"
                         "s_waitcnt lgkmcnt(0)"
                         : "=s"(ch) : "s"(pc));
            #pragma unroll
            for (int j = 0; j < 8; ++j) {
                int p  = ch[2 * j];
                int wb = ch[2 * j + 1];
                int s = p & 0xffff;
                int t = ((unsigned)p) >> 16;
                ushort xv = xu[s * ND + base_x];
                ushort rv = ru[t * ND + base_r];
                _Float16 pr = __builtin_bit_cast(_Float16, (unsigned short)xv)
                            * __builtin_bit_cast(_Float16, (unsigned short)rv);
                _Float16 wh = __builtin_bit_cast(_Float16,
                                                 (unsigned short)(wb & 0xffff));
                acc = fmaf((float)pr, (float)wh, acc);   // v_fma_mix candidate
            }
        }
    }
    if (n == hb) acc += query[b * ND + lane];
    A16[wv * 136 + 64 + lane] = (_Float16)acc;
    A16[wv * 136 + lane] = __builtin_bit_cast(_Float16, (unsigned short)xown);
    __syncthreads();
    if (wv < 4) {                       // MFMA: 4 waves cover 64 cols
        int m = lane & 15, quad = lane >> 4;
        int ncol = wv * 16 + m;
        floatx4 acc4 = {0.f, 0.f, 0.f, 0.f};
        #pragma unroll
        for (int k0 = 0; k0 < 128; k0 += 32) {
            half8 a = *(const half8*)&A16[m * 136 + k0 + quad * 8];
            half8 bfr = *(const half8*)&cwt[ncol * 128 + k0 + quad * 8];
            acc4 = __builtin_amdgcn_mfma_f32_16x16x32_f16(a, bfr, acc4, 0, 0, 0);
        }
        #pragma unroll
        for (int rg = 0; rg < 4; ++rg)
            sD[(quad * 4 + rg) * 65 + ncol] = acc4[rg];
    }
    __syncthreads();
    // LN: wave wv owns row wv (= node n)
    {
        float a = sD[wv * 65 + lane] + cb[lane];
        float s = a, s2 = a * a;
        #pragma unroll
        for (int o = 32; o > 0; o >>= 1) { s += __shfl_xor(s, o); s2 += __shfl_xor(s2, o); }
        float mu  = s * (1.f / ND);
        float var = s2 * (1.f / ND) - mu * mu;
        float hn  = (a - mu) * rsqrtf(var + LN_EPS) * g[lane] + bb[lane];
        float xvf = (float)A16[wv * 136 + lane];
        float v   = fmaxf(hn, 0.f) + xvf;
        xo16[(b * NN + n) * ND + lane] = __float2half(v);
    }
}

// score[b,t] = relu(concat(x[b,ti,:],query[b,:]) @ W1 + b1) @ W2 + b2
__global__ void final_score(const __half* __restrict__ x16, const float* __restrict__ query,
                            const int* __restrict__ t_index,
                            const float* __restrict__ w1, const float* __restrict__ b1,
                            const float* __restrict__ w2, const float* __restrict__ b2,
                            float* __restrict__ out) {
    int gid = blockIdx.x * 4 + (threadIdx.x >> 6);
    int lane = threadIdx.x & 63;
    int b = gid / NT;
    int ti = t_index[gid];
    float xv = __half2float(x16[(b * NN + ti) * ND + lane]);
    float qv = query[b * ND + lane];
    float a0 = b1[lane], a1 = b1[lane + 64];
    #pragma unroll 8
    for (int k = 0; k < ND; ++k) {
        float f = __shfl(xv, k);
        a0 += f * w1[k * 128 + lane];
        a1 += f * w1[k * 128 + lane + 64];
    }
    #pragma unroll 8
    for (int k = 0; k < ND; ++k) {
        float f = __shfl(qv, k);
        a0 += f * w1[(ND + k) * 128 + lane];
        a1 += f * w1[(ND + k) * 128 + lane + 64];
    }
    a0 = fmaxf(a0, 0.f);
    a1 = fmaxf(a1, 0.f);
    float p = a0 * w2[lane] + a1 * w2[lane + 64];
    #pragma unroll
    for (int o = 32; o > 0; o >>= 1) p += __shfl_xor(p, o);
    if (lane == 0) out[gid] = p + b2[0];
}

extern "C" void kernel_launch(void* const* d_in, const int* in_sizes, int n_in,
                              void* d_out, int out_size, void* d_ws, size_t ws_size,
                              hipStream_t stream) {
    const int*   edge_index  = (const int*)d_in[0];
    const int*   edge_type   = (const int*)d_in[1];
    const float* relrep      = (const float*)d_in[2];
    const int*   h_index     = (const int*)d_in[3];
    const int*   r_index     = (const int*)d_in[4];
    const int*   t_index     = (const int*)d_in[5];
    const float* edge_weight = (const float*)d_in[6];
    const float* rp_w1  = (const float*)d_in[7];
    const float* rp_b1  = (const float*)d_in[8];
    const float* rp_w2  = (const float*)d_in[9];
    const float* rp_b2  = (const float*)d_in[10];
    const float* conv_w = (const float*)d_in[11];
    const float* conv_b = (const float*)d_in[12];
    const float* ln_g   = (const float*)d_in[13];
    const float* ln_b   = (const float*)d_in[14];
    const float* mlp_w1 = (const float*)d_in[15];
    const float* mlp_b1 = (const float*)d_in[16];
    const float* mlp_w2 = (const float*)d_in[17];
    const float* mlp_b2 = (const float*)d_in[18];
    float* out = (float*)d_out;

    const int BND = NB * NN * ND;              // 5,120,000
    const int RELSZ = NR * NB * ND;            // 16384
    float*    ws     = (float*)d_ws;
    float*    query  = ws;                         // 256 f
    __half*   rel16  = (__half*)(query + 256);     // NL*RELSZ halves
    __half*   x16a   = rel16 + NL * RELSZ;         // BND halves
    __half*   x16b   = x16a + BND;                 // BND halves
    _Float16* cwt16  = (_Float16*)(x16b + BND);    // NL*8192 halves
    int2*     epack  = (int2*)(cwt16 + NL * 8192); // NN*CAP int2 (10.2 MB)
    int*      cnt    = (int*)(epack + NN * CAP);   // NN
    // total ≈ 32 MB

    // 9-dispatch graph
    prep1<<<3156, 256, 0, stream>>>(cnt, (int4*)epack, conv_w, cwt16,
                                    relrep, r_index, query,
                                    rp_w1, rp_b1, rp_w2, rp_b2, rel16);
    prep2<<<NE / 256, 256, 0, stream>>>(edge_index, edge_type, edge_weight,
                                        cnt, epack);

    __half* mc = x16a; __half* mn = x16b;
    fused_layer_first<<<NN / 4, 256, 0, stream>>>(rel16, cnt, epack,
                                                  query, h_index,
                                                  cwt16, conv_b, ln_g, ln_b, mc);
    for (int l = 1; l < NL; ++l) {
        fused_layer<<<NN / 8 * NB, 512, 0, stream>>>(mc, rel16 + l * RELSZ, cnt, epack,
                                                     query, h_index,
                                                     cwt16 + l * 8192, conv_b + l * ND,
                                                     ln_g + l * ND, ln_b + l * ND, mn);
        __half* th = mc; mc = mn; mn = th;
    }
    final_score<<<NB * NT / 4, 256, 0, stream>>>(mc, query, t_index,
                                                 mlp_w1, mlp_b1, mlp_w2, mlp_b2, out);
}